// Round 15
// baseline (330.002 us; speedup 1.0000x reference)
//
#include <hip/hip_runtime.h>
#include <hip/hip_bf16.h>

typedef __bf16 bf16;
typedef __bf16 bf16x4 __attribute__((ext_vector_type(4)));
typedef __bf16 bf16x8 __attribute__((ext_vector_type(8)));
typedef float f32x4 __attribute__((ext_vector_type(4)));

// Problem constants
#define BB 2
#define TT 4096
#define CC 512
#define HH 8
#define HD 64
#define BHD 16          // B*H
#define M_TOT 8192      // B*T

#define SCL (0.125f * 1.44269504f)    // 1/sqrt(64) * log2(e), folded into q

#if __has_builtin(__builtin_amdgcn_exp2f)
#define EXP2F(x) __builtin_amdgcn_exp2f(x)
#else
#define EXP2F(x) exp2f(x)
#endif

#define GLDS(gptr, lptr)                                                     \
  __builtin_amdgcn_global_load_lds(                                          \
      (const __attribute__((address_space(1))) void*)(gptr),                 \
      (__attribute__((address_space(3))) void*)(lptr), 16, 0, 0)

// ---------------------------------------------------------------------------
// convert X f32 -> bf16 (element-wise)
// ---------------------------------------------------------------------------
__global__ __launch_bounds__(256) void convert_x_kernel(
    const float* __restrict__ X, bf16* __restrict__ Xb) {
  const size_t i0 = ((size_t)blockIdx.x * 256 + threadIdx.x) * 16;
  const float4* p = (const float4*)(X + i0);
#pragma unroll
  for (int c = 0; c < 2; ++c) {
    float4 a = p[c * 2], b = p[c * 2 + 1];
    bf16x8 v;
    v[0] = (bf16)a.x; v[1] = (bf16)a.y; v[2] = (bf16)a.z; v[3] = (bf16)a.w;
    v[4] = (bf16)b.x; v[5] = (bf16)b.y; v[6] = (bf16)b.z; v[7] = (bf16)b.w;
    *(bf16x8*)&Xb[i0 + c * 8] = v;
  }
}

// ---------------------------------------------------------------------------
// transpose+convert both weights: W [K][N] f32 -> WT [N][K] bf16. grid 256.
// ---------------------------------------------------------------------------
__global__ __launch_bounds__(256) void transpose_w_kernel(
    const float* __restrict__ Wq, const float* __restrict__ Wo,
    bf16* __restrict__ WQT, bf16* __restrict__ WOT) {
  __shared__ float tile[64][65];
  int b = blockIdx.x;
  const float* W; bf16* WT; int N, n0, k0;
  if (b < 192) { W = Wq; WT = WQT; N = 1536; n0 = (b % 24) * 64; k0 = (b / 24) * 64; }
  else { b -= 192; W = Wo; WT = WOT; N = 512; n0 = (b & 7) * 64; k0 = (b >> 3) * 64; }
  const int t = threadIdx.x;
  const int rr = t >> 4, cc4 = (t & 15) * 4;
#pragma unroll
  for (int i = 0; i < 4; ++i) {
    float4 v = *(const float4*)&W[(size_t)(k0 + rr + i * 16) * N + n0 + cc4];
    tile[rr + i * 16][cc4 + 0] = v.x;
    tile[rr + i * 16][cc4 + 1] = v.y;
    tile[rr + i * 16][cc4 + 2] = v.z;
    tile[rr + i * 16][cc4 + 3] = v.w;
  }
  __syncthreads();
#pragma unroll
  for (int i = 0; i < 4; ++i) {
    const int nn = rr + i * 16;
    bf16x4 o;
#pragma unroll
    for (int j = 0; j < 4; ++j) o[j] = (bf16)tile[cc4 + j][nn];
    *(bf16x4*)&WT[(size_t)(n0 + nn) * 512 + k0 + cc4] = o;
  }
}

// ---------------------------------------------------------------------------
// GEMM 1: qkv = xb @ wqt^T. V stored permuted-within-64 t-blocks:
// t -> (t&3) | b<<2 | hi2<<3 | h2<<5  (b=(t>>4)&1, hi2=(t>>2)&3, h2=(t>>5)&1)
// so each attn PV B-fragment is one contiguous 16B read.
// ---------------------------------------------------------------------------
__global__ __launch_bounds__(256) void gemm_qkv_kernel(
    const bf16* __restrict__ Xb, const bf16* __restrict__ Wt,
    bf16* __restrict__ qw, bf16* __restrict__ kw, bf16* __restrict__ vw) {
  __shared__ __align__(16) bf16 As[128 * 64];
  __shared__ __align__(16) bf16 Bs[128 * 64];
  const int tid = threadIdx.x;
  const int wid = tid >> 6, lane = tid & 63, ln = lane & 15, hi = lane >> 4;
  const int wr = wid >> 1, wc = wid & 1;
  const int m0 = blockIdx.x * 128, n0 = blockIdx.y * 128;
  const int srow = lane >> 3, srcc = (lane & 7) ^ srow;

  f32x4 acc[4][4] = {};

  for (int k0 = 0; k0 < 512; k0 += 64) {
    __syncthreads();
#pragma unroll
    for (int i = 0; i < 4; ++i) {
      const int rb = 32 * wid + 8 * i;      // wave-uniform base row
      GLDS(&Xb[(size_t)(m0 + rb + srow) * 512 + k0 + srcc * 8], &As[rb * 64]);
      GLDS(&Wt[(size_t)(n0 + rb + srow) * 512 + k0 + srcc * 8], &Bs[rb * 64]);
    }
    __syncthreads();

    bf16x8 af[4][2], bfr[4][2];
#pragma unroll
    for (int mi = 0; mi < 4; ++mi) {
      const int row = wr * 64 + mi * 16 + ln, rs = row & 7;
      af[mi][0] = *(const bf16x8*)&As[row * 64 + ((hi ^ rs) * 8)];
      af[mi][1] = *(const bf16x8*)&As[row * 64 + (((4 + hi) ^ rs) * 8)];
    }
#pragma unroll
    for (int ni = 0; ni < 4; ++ni) {
      const int row = wc * 64 + ni * 16 + ln, rs = row & 7;
      bfr[ni][0] = *(const bf16x8*)&Bs[row * 64 + ((hi ^ rs) * 8)];
      bfr[ni][1] = *(const bf16x8*)&Bs[row * 64 + (((4 + hi) ^ rs) * 8)];
    }
#pragma unroll
    for (int mi = 0; mi < 4; ++mi)
#pragma unroll
      for (int ni = 0; ni < 4; ++ni) {
        acc[mi][ni] = __builtin_amdgcn_mfma_f32_16x16x32_bf16(af[mi][0], bfr[ni][0], acc[mi][ni], 0, 0, 0);
        acc[mi][ni] = __builtin_amdgcn_mfma_f32_16x16x32_bf16(af[mi][1], bfr[ni][1], acc[mi][ni], 0, 0, 0);
      }
  }

  // D: col = lane&15, row = (lane>>4)*4 + reg
#pragma unroll
  for (int mi = 0; mi < 4; ++mi) {
    int rowb = m0 + wr * 64 + mi * 16 + hi * 4;
    int b = rowb >> 12, t0 = rowb & 4095;
#pragma unroll
    for (int ni = 0; ni < 4; ++ni) {
      int n = n0 + wc * 64 + ni * 16 + ln;
      int which = n >> 9, c = n & 511, h = c >> 6, d = c & 63;
      if (which == 2) {
        bf16x4 pv;
#pragma unroll
        for (int r = 0; r < 4; ++r) pv[r] = (bf16)acc[mi][ni][r];
        const int tb = t0 & 63;    // multiple of 4
        const int paddr = (((tb >> 4) & 1) << 2) | (((tb >> 2) & 3) << 3) |
                          ((tb >> 5) << 5);
        *(bf16x4*)&vw[((size_t)(b * HH + h) * HD + d) * TT + (t0 & ~63) + paddr] = pv;
      } else {
        bf16* dst = which ? kw : qw;
        const float sc = which ? 1.0f : SCL;
#pragma unroll
        for (int r = 0; r < 4; ++r)
          dst[((size_t)(b * HH + h) * TT + t0 + r) * HD + d] = (bf16)(acc[mi][ni][r] * sc);
      }
    }
  }
}

// ---------------------------------------------------------------------------
// Flash attention pieces, BARRIER-FREE: no LDS. Each wave is independent:
// 32 q-rows x 8-tile kv chunk, K/V fragments read directly from global (L2).
// XCD-aware: bid%8 selects a group owning 2 heads -> K/V L2-resident.
// 2304 blocks x 256 thr (4 waves). po/pl layout identical to R14 (1152 pieces).
// ---------------------------------------------------------------------------
__global__ __launch_bounds__(256, 4) void attn_piece_kernel(
    const bf16* __restrict__ qw, const bf16* __restrict__ kw,
    const bf16* __restrict__ vt,
    bf16* __restrict__ po, float* __restrict__ pl) {
  const int tid = threadIdx.x;
  const int wid = tid >> 6, lane = tid & 63, ln = lane & 15, hi = lane >> 4;

  // work-unit mapping: group g = bid&7 (XCD), unit within group
  const int g = blockIdx.x & 7;
  int u = (blockIdx.x >> 3) * 4 + wid;        // 0..1151
  int bh = g;
  if (u >= 576) { bh = g + 8; u -= 576; }
  int qb4 = 15;                                // heavy-first: qb4 descending
  while (qb4 > 0) {
    const int cnt = 8 * ((4 * qb4 + 11) >> 3); // 8*ceil(ntot/8)
    if (u < cnt) break;
    u -= cnt;
    --qb4;
  }
  const int chunk = u >> 3, wavein = u & 7;
  const int ntot = 4 * qb4 + 4;
  const int t0c = chunk * 8;
  const int t1c = (t0c + 8 < ntot) ? (t0c + 8) : ntot;
  const int q0w = qb4 * 256 + wavein * 32;
  const int t1w0 = ((q0w + 31) >> 6) + 1;
  const int t1w = (t1c < t1w0) ? t1c : t1w0;   // causal clamp

  // piece id (same layout as combine expects)
  const int K = (qb4 + 2) >> 1;
  static const int OFF[9] = {0, 1120, 1056, 960, 832, 672, 480, 256, 0};
  const int pid = OFF[K] + ((2 * K - 1) - qb4) * 16 * K + bh * K + chunk;

  const size_t kb = (size_t)bh * TT * HD, vb = (size_t)bh * HD * TT;

  bf16x8 qf[2][2];
#pragma unroll
  for (int qi = 0; qi < 2; ++qi)
#pragma unroll
    for (int h = 0; h < 2; ++h)
      qf[qi][h] = *(const bf16x8*)&qw[((size_t)bh * TT + q0w + qi * 16 + ln) * HD + h * 32 + hi * 8];

  f32x4 o[2][4] = {};
  f32x4 osum[2] = {};

  bf16x8 vones;
#pragma unroll
  for (int j = 0; j < 8; ++j) vones[j] = (bf16)1.0f;

  // running global pointers (per-lane)
  const bf16* kptr = kw + kb + (size_t)(t0c * 64 + ln) * HD + hi * 8;
  const bf16* vptr[4];
#pragma unroll
  for (int db = 0; db < 4; ++db)
    vptr[db] = vt + vb + (size_t)(db * 16 + ln) * TT + t0c * 64 + hi * 8;

  for (int t = t0c; t < t1w; ++t) {
    const int kv0 = t * 64;
    // ---- load K fragments (8 x b128, L2)
    bf16x8 kf0[4], kf1[4];
#pragma unroll
    for (int kt = 0; kt < 4; ++kt) {
      kf0[kt] = *(const bf16x8*)(kptr + kt * 1024);        // k 0..31 half
      kf1[kt] = *(const bf16x8*)(kptr + kt * 1024 + 32);   // k 32..63 half
    }
    // ---- load V fragments (8 x b128, L2); permuted layout => contiguous
    bf16x8 vf[4][2];
#pragma unroll
    for (int db = 0; db < 4; ++db)
#pragma unroll
      for (int h2 = 0; h2 < 2; ++h2)
        vf[db][h2] = *(const bf16x8*)(vptr[db] + h2 * 32);
    kptr += 4096;
#pragma unroll
    for (int db = 0; db < 4; ++db) vptr[db] += 64;

    // ---- QK^T swapped: D[kv][q], col=ln=q
    f32x4 s[2][4];
    __builtin_amdgcn_s_setprio(1);
#pragma unroll
    for (int kt = 0; kt < 4; ++kt)
#pragma unroll
      for (int qi = 0; qi < 2; ++qi) {
        f32x4 a = {};
        a = __builtin_amdgcn_mfma_f32_16x16x32_bf16(kf0[kt], qf[qi][0], a, 0, 0, 0);
        a = __builtin_amdgcn_mfma_f32_16x16x32_bf16(kf1[kt], qf[qi][1], a, 0, 0, 0);
        s[qi][kt] = a;
      }
    __builtin_amdgcn_s_setprio(0);

    // ---- causal mask
#pragma unroll
    for (int qi = 0; qi < 2; ++qi) {
      if (kv0 + 63 > q0w + qi * 16) {
        const int qg = q0w + qi * 16 + ln;
#pragma unroll
        for (int kt = 0; kt < 4; ++kt)
#pragma unroll
          for (int r = 0; r < 4; ++r)
            if (kv0 + kt * 16 + hi * 4 + r > qg) s[qi][kt][r] = -1e30f;
      }
    }
    // ---- exp (no max: scores bounded, softmax shift-invariant)
#pragma unroll
    for (int qi = 0; qi < 2; ++qi)
#pragma unroll
      for (int kt = 0; kt < 4; ++kt)
#pragma unroll
        for (int r = 0; r < 4; ++r) s[qi][kt][r] = EXP2F(s[qi][kt][r]);
    // pack P: slot j of half h2 -> kv = 32*h2 + 16*(j>>2) + 4*hi + (j&3)
    bf16x8 pa[2][2];
#pragma unroll
    for (int qi = 0; qi < 2; ++qi)
#pragma unroll
      for (int h2 = 0; h2 < 2; ++h2)
#pragma unroll
        for (int j = 0; j < 8; ++j)
          pa[qi][h2][j] = (bf16)s[qi][h2 * 2 + (j >> 2)][j & 3];

    // ---- PV + ones-column row sums
    __builtin_amdgcn_s_setprio(1);
#pragma unroll
    for (int qi = 0; qi < 2; ++qi) {
      osum[qi] = __builtin_amdgcn_mfma_f32_16x16x32_bf16(pa[qi][0], vones, osum[qi], 0, 0, 0);
      osum[qi] = __builtin_amdgcn_mfma_f32_16x16x32_bf16(pa[qi][1], vones, osum[qi], 0, 0, 0);
    }
#pragma unroll
    for (int db = 0; db < 4; ++db)
#pragma unroll
      for (int h2 = 0; h2 < 2; ++h2)
#pragma unroll
        for (int qi = 0; qi < 2; ++qi)
          o[qi][db] = __builtin_amdgcn_mfma_f32_16x16x32_bf16(pa[qi][h2], vf[db][h2], o[qi][db], 0, 0, 0);
    __builtin_amdgcn_s_setprio(0);
  }

  // ---- write partials: unnormalized O (bf16) [256][64], rowsum [256]
  {
    bf16* ob = po + (size_t)pid * 16384;
#pragma unroll
    for (int qi = 0; qi < 2; ++qi)
#pragma unroll
      for (int db = 0; db < 4; ++db)
#pragma unroll
        for (int r = 0; r < 4; ++r)
          ob[(wavein * 32 + qi * 16 + hi * 4 + r) * 64 + db * 16 + ln] = (bf16)o[qi][db][r];
    if (ln == 0) {
#pragma unroll
      for (int qi = 0; qi < 2; ++qi)
#pragma unroll
        for (int r = 0; r < 4; ++r)
          pl[pid * 256 + wavein * 32 + qi * 16 + hi * 4 + r] = osum[qi][r];
    }
  }
}

// ---------------------------------------------------------------------------
// Combine: merge 1-8 chunks -> normalized bf16 attention output [bh][t][d]
// grid 512 = (qb4 0..15) x (bh 0..15) x (half 0..1); 128 q-rows per block
// ---------------------------------------------------------------------------
__global__ __launch_bounds__(256) void attn_combine_kernel(
    const bf16* __restrict__ po, const float* __restrict__ pl,
    bf16* __restrict__ aw) {
  const int cb = blockIdx.x;
  const int qb4 = 15 - (cb >> 5);
  const int r5 = cb & 31;
  const int bh = r5 >> 1, half = r5 & 1;
  const int tid = threadIdx.x;
  const int q_ = half * 128 + (tid >> 1), dc = (tid & 1) * 32;

  const int k = (qb4 + 2) >> 1;          // nch
  static const int OFF[9] = {0, 1120, 1056, 960, 832, 672, 480, 256, 0};
  const int p0 = OFF[k] + ((2 * k - 1) - qb4) * 16 * k + bh * k;

  float sum = 0.f;
  for (int c = 0; c < k; ++c) sum += pl[(p0 + c) * 256 + q_];
  const float inv = 1.0f / sum;

  float acc[32] = {};
  for (int c = 0; c < k; ++c) {
    const bf16* ob = po + (size_t)(p0 + c) * 16384 + q_ * 64 + dc;
#pragma unroll
    for (int cc = 0; cc < 4; ++cc) {
      bf16x8 x = *(const bf16x8*)&ob[cc * 8];
#pragma unroll
      for (int j = 0; j < 8; ++j) acc[cc * 8 + j] += (float)x[j];
    }
  }
  bf16* dst = aw + ((size_t)bh * TT + qb4 * 256 + q_) * 64 + dc;
#pragma unroll
  for (int cc = 0; cc < 4; ++cc) {
    bf16x8 outv;
#pragma unroll
    for (int j = 0; j < 8; ++j) outv[j] = (bf16)(acc[cc * 8 + j] * inv);
    *(bf16x8*)&dst[cc * 8] = outv;
  }
}

// ---------------------------------------------------------------------------
// GEMM 3: out = attn @ wot^T
// ---------------------------------------------------------------------------
__global__ __launch_bounds__(256) void gemm_out_kernel(
    const bf16* __restrict__ A, const bf16* __restrict__ Wot,
    float* __restrict__ out) {
  __shared__ __align__(16) bf16 As[128 * 64];
  __shared__ __align__(16) bf16 Bs[64 * 64];
  const int tid = threadIdx.x;
  const int wid = tid >> 6, lane = tid & 63, ln = lane & 15, hi = lane >> 4;
  const int wr = wid >> 1, wc = wid & 1;
  const int m0 = blockIdx.x * 128, n0 = blockIdx.y * 64;
  const int srow = lane >> 3, srcc = (lane & 7) ^ srow;

  f32x4 acc[4][2] = {};

  for (int k0 = 0; k0 < 512; k0 += 64) {
    const int h = k0 >> 6;
    __syncthreads();
#pragma unroll
    for (int i = 0; i < 4; ++i) {
      const int rb = 32 * wid + 8 * i;
      const int m = m0 + rb + srow;
      const int b = m >> 12, t = m & 4095;
      GLDS(&A[((size_t)(b * HH + h) * TT + t) * HD + srcc * 8], &As[rb * 64]);
    }
#pragma unroll
    for (int i = 0; i < 2; ++i) {
      const int rb = 16 * wid + 8 * i;
      GLDS(&Wot[(size_t)(n0 + rb + srow) * 512 + k0 + srcc * 8], &Bs[rb * 64]);
    }
    __syncthreads();

    bf16x8 af[4][2], bfr[2][2];
#pragma unroll
    for (int mi = 0; mi < 4; ++mi) {
      const int row = wr * 64 + mi * 16 + ln, rs = row & 7;
      af[mi][0] = *(const bf16x8*)&As[row * 64 + ((hi ^ rs) * 8)];
      af[mi][1] = *(const bf16x8*)&As[row * 64 + (((4 + hi) ^ rs) * 8)];
    }
#pragma unroll
    for (int ni = 0; ni < 2; ++ni) {
      const int row = wc * 32 + ni * 16 + ln, rs = row & 7;
      bfr[ni][0] = *(const bf16x8*)&Bs[row * 64 + ((hi ^ rs) * 8)];
      bfr[ni][1] = *(const bf16x8*)&Bs[row * 64 + (((4 + hi) ^ rs) * 8)];
    }
#pragma unroll
    for (int mi = 0; mi < 4; ++mi)
#pragma unroll
      for (int ni = 0; ni < 2; ++ni) {
        acc[mi][ni] = __builtin_amdgcn_mfma_f32_16x16x32_bf16(af[mi][0], bfr[ni][0], acc[mi][ni], 0, 0, 0);
        acc[mi][ni] = __builtin_amdgcn_mfma_f32_16x16x32_bf16(af[mi][1], bfr[ni][1], acc[mi][ni], 0, 0, 0);
      }
  }

#pragma unroll
  for (int mi = 0; mi < 4; ++mi) {
    int rowb = m0 + wr * 64 + mi * 16 + hi * 4;
#pragma unroll
    for (int ni = 0; ni < 2; ++ni) {
      int n = n0 + wc * 32 + ni * 16 + ln;
#pragma unroll
      for (int r = 0; r < 4; ++r)
        out[(size_t)(rowb + r) * 512 + n] = acc[mi][ni][r];
    }
  }
}

extern "C" void kernel_launch(void* const* d_in, const int* in_sizes, int n_in,
                              void* d_out, int out_size, void* d_ws, size_t ws_size,
                              hipStream_t stream) {
  const float* x = (const float*)d_in[0];
  const float* w_qkv = (const float*)d_in[1];
  const float* w_out = (const float*)d_in[2];
  float* out = (float*)d_out;

  const size_t QKV_ELEMS = (size_t)BHD * TT * HD;   // 4,194,304
  bf16* qw = (bf16*)d_ws;
  bf16* kw = qw + QKV_ELEMS;
  bf16* vw = kw + QKV_ELEMS;       // transposed+permuted layout [bh][d][t']
  bf16* aw = vw + QKV_ELEMS;
  bf16* po = aw + QKV_ELEMS;                         // 1152 x 16384 bf16 = 37.7MB
  float* pl = (float*)(po + (size_t)1152 * 16384);   // 1152 x 256 f32
  bf16* wqt = (bf16*)(pl + (size_t)1152 * 256);      // 1536 x 512 bf16
  bf16* wot = wqt + (size_t)1536 * 512;              // 512 x 512 bf16
  bf16* xb = po;   // alias: xb only live before attn_piece writes po

  convert_x_kernel<<<1024, 256, 0, stream>>>(x, xb);
  transpose_w_kernel<<<256, 256, 0, stream>>>(w_qkv, w_out, wqt, wot);
  gemm_qkv_kernel<<<dim3(M_TOT / 128, 1536 / 128), 256, 0, stream>>>(xb, wqt, qw, kw, vw);
  attn_piece_kernel<<<2304, 256, 0, stream>>>(qw, kw, vw, po, pl);
  attn_combine_kernel<<<512, 256, 0, stream>>>(po, pl, aw);
  gemm_out_kernel<<<dim3(M_TOT / 128, 512 / 64), 256, 0, stream>>>(aw, wot, out);
}

// Round 16
// 108.059 us; speedup vs baseline: 3.0539x; 3.0539x over previous
//
#include <hip/hip_runtime.h>
#include <hip/hip_bf16.h>

typedef __bf16 bf16;
typedef __bf16 bf16x4 __attribute__((ext_vector_type(4)));
typedef __bf16 bf16x8 __attribute__((ext_vector_type(8)));
typedef float f32x4 __attribute__((ext_vector_type(4)));

// Problem constants
#define BB 2
#define TT 4096
#define CC 512
#define HH 8
#define HD 64
#define BHD 16          // B*H
#define M_TOT 8192      // B*T

#define SCL (0.125f * 1.44269504f)    // 1/sqrt(64) * log2(e), folded into q

#if __has_builtin(__builtin_amdgcn_exp2f)
#define EXP2F(x) __builtin_amdgcn_exp2f(x)
#else
#define EXP2F(x) exp2f(x)
#endif

#define GLDS(gptr, lptr)                                                     \
  __builtin_amdgcn_global_load_lds(                                          \
      (const __attribute__((address_space(1))) void*)(gptr),                 \
      (__attribute__((address_space(3))) void*)(lptr), 16, 0, 0)

// ---------------------------------------------------------------------------
// convert X f32 -> bf16 (element-wise)
// ---------------------------------------------------------------------------
__global__ __launch_bounds__(256) void convert_x_kernel(
    const float* __restrict__ X, bf16* __restrict__ Xb) {
  const size_t i0 = ((size_t)blockIdx.x * 256 + threadIdx.x) * 16;
  const float4* p = (const float4*)(X + i0);
#pragma unroll
  for (int c = 0; c < 2; ++c) {
    float4 a = p[c * 2], b = p[c * 2 + 1];
    bf16x8 v;
    v[0] = (bf16)a.x; v[1] = (bf16)a.y; v[2] = (bf16)a.z; v[3] = (bf16)a.w;
    v[4] = (bf16)b.x; v[5] = (bf16)b.y; v[6] = (bf16)b.z; v[7] = (bf16)b.w;
    *(bf16x8*)&Xb[i0 + c * 8] = v;
  }
}

// ---------------------------------------------------------------------------
// transpose+convert both weights: W [K][N] f32 -> WT [N][K] bf16. grid 256.
// ---------------------------------------------------------------------------
__global__ __launch_bounds__(256) void transpose_w_kernel(
    const float* __restrict__ Wq, const float* __restrict__ Wo,
    bf16* __restrict__ WQT, bf16* __restrict__ WOT) {
  __shared__ float tile[64][65];
  int b = blockIdx.x;
  const float* W; bf16* WT; int N, n0, k0;
  if (b < 192) { W = Wq; WT = WQT; N = 1536; n0 = (b % 24) * 64; k0 = (b / 24) * 64; }
  else { b -= 192; W = Wo; WT = WOT; N = 512; n0 = (b & 7) * 64; k0 = (b >> 3) * 64; }
  const int t = threadIdx.x;
  const int rr = t >> 4, cc4 = (t & 15) * 4;
#pragma unroll
  for (int i = 0; i < 4; ++i) {
    float4 v = *(const float4*)&W[(size_t)(k0 + rr + i * 16) * N + n0 + cc4];
    tile[rr + i * 16][cc4 + 0] = v.x;
    tile[rr + i * 16][cc4 + 1] = v.y;
    tile[rr + i * 16][cc4 + 2] = v.z;
    tile[rr + i * 16][cc4 + 3] = v.w;
  }
  __syncthreads();
#pragma unroll
  for (int i = 0; i < 4; ++i) {
    const int nn = rr + i * 16;
    bf16x4 o;
#pragma unroll
    for (int j = 0; j < 4; ++j) o[j] = (bf16)tile[cc4 + j][nn];
    *(bf16x4*)&WT[(size_t)(n0 + nn) * 512 + k0 + cc4] = o;
  }
}

// ---------------------------------------------------------------------------
// GEMM 1: qkv = xb @ wqt^T. V stored permuted-within-64 t-blocks:
// t -> (t&3) | b<<2 | hi2<<3 | h2<<5  (b=(t>>4)&1, hi2=(t>>2)&3, h2=(t>>5)&1)
// so each attn PV B-fragment is one contiguous 16B LDS read.
// ---------------------------------------------------------------------------
__global__ __launch_bounds__(256) void gemm_qkv_kernel(
    const bf16* __restrict__ Xb, const bf16* __restrict__ Wt,
    bf16* __restrict__ qw, bf16* __restrict__ kw, bf16* __restrict__ vw) {
  __shared__ __align__(16) bf16 As[128 * 64];
  __shared__ __align__(16) bf16 Bs[128 * 64];
  const int tid = threadIdx.x;
  const int wid = tid >> 6, lane = tid & 63, ln = lane & 15, hi = lane >> 4;
  const int wr = wid >> 1, wc = wid & 1;
  const int m0 = blockIdx.x * 128, n0 = blockIdx.y * 128;
  const int srow = lane >> 3, srcc = (lane & 7) ^ srow;

  f32x4 acc[4][4] = {};

  for (int k0 = 0; k0 < 512; k0 += 64) {
    __syncthreads();
#pragma unroll
    for (int i = 0; i < 4; ++i) {
      const int rb = 32 * wid + 8 * i;      // wave-uniform base row
      GLDS(&Xb[(size_t)(m0 + rb + srow) * 512 + k0 + srcc * 8], &As[rb * 64]);
      GLDS(&Wt[(size_t)(n0 + rb + srow) * 512 + k0 + srcc * 8], &Bs[rb * 64]);
    }
    __syncthreads();

    bf16x8 af[4][2], bfr[4][2];
#pragma unroll
    for (int mi = 0; mi < 4; ++mi) {
      const int row = wr * 64 + mi * 16 + ln, rs = row & 7;
      af[mi][0] = *(const bf16x8*)&As[row * 64 + ((hi ^ rs) * 8)];
      af[mi][1] = *(const bf16x8*)&As[row * 64 + (((4 + hi) ^ rs) * 8)];
    }
#pragma unroll
    for (int ni = 0; ni < 4; ++ni) {
      const int row = wc * 64 + ni * 16 + ln, rs = row & 7;
      bfr[ni][0] = *(const bf16x8*)&Bs[row * 64 + ((hi ^ rs) * 8)];
      bfr[ni][1] = *(const bf16x8*)&Bs[row * 64 + (((4 + hi) ^ rs) * 8)];
    }
#pragma unroll
    for (int mi = 0; mi < 4; ++mi)
#pragma unroll
      for (int ni = 0; ni < 4; ++ni) {
        acc[mi][ni] = __builtin_amdgcn_mfma_f32_16x16x32_bf16(af[mi][0], bfr[ni][0], acc[mi][ni], 0, 0, 0);
        acc[mi][ni] = __builtin_amdgcn_mfma_f32_16x16x32_bf16(af[mi][1], bfr[ni][1], acc[mi][ni], 0, 0, 0);
      }
  }

  // D: col = lane&15, row = (lane>>4)*4 + reg
#pragma unroll
  for (int mi = 0; mi < 4; ++mi) {
    int rowb = m0 + wr * 64 + mi * 16 + hi * 4;
    int b = rowb >> 12, t0 = rowb & 4095;
#pragma unroll
    for (int ni = 0; ni < 4; ++ni) {
      int n = n0 + wc * 64 + ni * 16 + ln;
      int which = n >> 9, c = n & 511, h = c >> 6, d = c & 63;
      if (which == 2) {
        bf16x4 pv;
#pragma unroll
        for (int r = 0; r < 4; ++r) pv[r] = (bf16)acc[mi][ni][r];
        const int tb = t0 & 63;    // multiple of 4
        const int paddr = (((tb >> 4) & 1) << 2) | (((tb >> 2) & 3) << 3) |
                          ((tb >> 5) << 5);
        *(bf16x4*)&vw[((size_t)(b * HH + h) * HD + d) * TT + (t0 & ~63) + paddr] = pv;
      } else {
        bf16* dst = which ? kw : qw;
        const float sc = which ? 1.0f : SCL;
#pragma unroll
        for (int r = 0; r < 4; ++r)
          dst[((size_t)(b * HH + h) * TT + t0 + r) * HD + d] = (bf16)(acc[mi][ni][r] * sc);
      }
    }
  }
}

// ---------------------------------------------------------------------------
// Flash attention pieces (R14 structure): 512 threads = 8 waves x 32 q-rows,
// KV tile 64, 8-tile chunks. XCD-LOCAL WORK MAPPING: group g = bid&7 (XCD)
// owns heads {g, g+8}, processed head-major (2MB working set < 4MB L2/XCD),
// heavy-first (qb4 desc) within each head. pid formula (combine) unchanged.
// ---------------------------------------------------------------------------
__global__ __launch_bounds__(512, 4) void attn_piece_kernel(
    const bf16* __restrict__ qw, const bf16* __restrict__ kw,
    const bf16* __restrict__ vt,
    bf16* __restrict__ po, float* __restrict__ pl) {
  __shared__ __align__(16) bf16 Ks[2][64 * 64];
  __shared__ __align__(16) bf16 Vs[2][64 * 64];     // [d][kv'] permuted
  const int tid = threadIdx.x;
  const int wid = tid >> 6, lane = tid & 63, ln = lane & 15, hi = lane >> 4;

  // ---- XCD-local mapping: 1152 blocks = 8 groups x 144 units
  int qb4, bh, chunk;
  {
    const int g = blockIdx.x & 7;
    int u = blockIdx.x >> 3;            // 0..143
    bh = g;
    if (u >= 72) { bh = g + 8; u -= 72; }
    qb4 = 15;
    for (;;) {
      const int Kb = (qb4 + 2) >> 1;
      if (u < Kb) break;
      u -= Kb;
      --qb4;
    }
    chunk = u;
  }
  const int ntot = 4 * qb4 + 4;
  const int t0c = chunk * 8;
  const int t1 = (t0c + 8 < ntot) ? (t0c + 8) : ntot;

  // piece id (same layout as combine expects)
  const int K = (qb4 + 2) >> 1;
  static const int OFF[9] = {0, 1120, 1056, 960, 832, 672, 480, 256, 0};
  const int pid = OFF[K] + ((2 * K - 1) - qb4) * 16 * K + bh * K + chunk;

  const int q0w = qb4 * 256 + wid * 32;   // wave covers 32 q rows (2 qi)

  const int rbase = 8 * wid + (lane >> 3);       // 0..63
  const int srcch = (lane & 7) ^ (lane >> 3);    // pre-swizzled source chunk
  const size_t kb = (size_t)bh * TT * HD, vb = (size_t)bh * HD * TT;

  bf16x8 qf[2][2];
#pragma unroll
  for (int qi = 0; qi < 2; ++qi)
#pragma unroll
    for (int h = 0; h < 2; ++h)
      qf[qi][h] = *(const bf16x8*)&qw[((size_t)bh * TT + q0w + qi * 16 + ln) * HD + h * 32 + hi * 8];

  // ---- hoisted LDS read pointers (loop-invariant; buf folds into ds offset)
  const bf16* kp[4][2];
#pragma unroll
  for (int kt = 0; kt < 4; ++kt) {
    const int krow = kt * 16 + ln;
    kp[kt][0] = &Ks[0][krow * 64 + ((hi ^ (ln & 7)) * 8)];
    kp[kt][1] = &Ks[0][krow * 64 + (((4 + hi) ^ (ln & 7)) * 8)];
  }
  const bf16* vp[4][2];   // single b128 per (db,h2): chunk (4h2+hi)^(d&7)
#pragma unroll
  for (int db = 0; db < 4; ++db) {
    const int d = db * 16 + ln, rowb = d * 64, dx = d & 7;
#pragma unroll
    for (int h2 = 0; h2 < 2; ++h2)
      vp[db][h2] = &Vs[0][rowb + (((4 * h2 + hi) ^ dx) * 8)];
  }

  f32x4 o[2][4] = {};
  f32x4 osum[2] = {};

  bf16x8 vones;
#pragma unroll
  for (int j = 0; j < 8; ++j) vones[j] = (bf16)1.0f;

  // prologue stage tile t0c into buf 0 (1 GLDS each for K,V per thread)
  {
    const int kv = t0c * 64;
    GLDS(kw + kb + (size_t)(kv + rbase) * HD + srcch * 8, &Ks[0][(8 * wid) * 64]);
    GLDS(vt + vb + (size_t)rbase * TT + kv + srcch * 8, &Vs[0][(8 * wid) * 64]);
  }
  const bf16* pk0 = kw + kb + (size_t)((t0c + 1) * 64 + rbase) * HD + srcch * 8;
  const bf16* pv0 = vt + vb + (size_t)rbase * TT + (t0c + 1) * 64 + srcch * 8;
  __syncthreads();

#define TILE(t_, BUF) do {                                                   \
    const int kv0 = (t_) * 64;                                               \
    if ((t_) + 1 < t1) {                                                     \
      GLDS(pk0, &Ks[(BUF) ^ 1][(8 * wid) * 64]);                             \
      GLDS(pv0, &Vs[(BUF) ^ 1][(8 * wid) * 64]);                             \
      pk0 += (size_t)64 * HD; pv0 += 64;                                     \
    }                                                                        \
    if (kv0 <= q0w + 31) {                                                   \
      f32x4 s[2][4];                                                         \
      __builtin_amdgcn_s_setprio(1);                                         \
      _Pragma("unroll")                                                      \
      for (int kt = 0; kt < 4; ++kt) {                                       \
        bf16x8 kf0 = *(const bf16x8*)(kp[kt][0] + (BUF) * 4096);             \
        bf16x8 kf1 = *(const bf16x8*)(kp[kt][1] + (BUF) * 4096);             \
        _Pragma("unroll")                                                    \
        for (int qi = 0; qi < 2; ++qi) {                                     \
          f32x4 a = {};                                                      \
          a = __builtin_amdgcn_mfma_f32_16x16x32_bf16(kf0, qf[qi][0], a, 0, 0, 0); \
          a = __builtin_amdgcn_mfma_f32_16x16x32_bf16(kf1, qf[qi][1], a, 0, 0, 0); \
          s[qi][kt] = a;                                                     \
        }                                                                    \
      }                                                                      \
      __builtin_amdgcn_s_setprio(0);                                         \
      _Pragma("unroll")                                                      \
      for (int qi = 0; qi < 2; ++qi) {                                       \
        if (kv0 + 63 > q0w + qi * 16) {                                      \
          const int qg = q0w + qi * 16 + ln;                                 \
          _Pragma("unroll")                                                  \
          for (int kt = 0; kt < 4; ++kt)                                     \
            _Pragma("unroll")                                                \
            for (int r = 0; r < 4; ++r)                                      \
              if (kv0 + kt * 16 + hi * 4 + r > qg) s[qi][kt][r] = -1e30f;    \
        }                                                                    \
      }                                                                      \
      _Pragma("unroll")                                                      \
      for (int qi = 0; qi < 2; ++qi)                                         \
        _Pragma("unroll")                                                    \
        for (int kt = 0; kt < 4; ++kt)                                       \
          _Pragma("unroll")                                                  \
          for (int r = 0; r < 4; ++r) s[qi][kt][r] = EXP2F(s[qi][kt][r]);    \
      bf16x8 pa[2][2];                                                       \
      _Pragma("unroll")                                                      \
      for (int qi = 0; qi < 2; ++qi)                                         \
        _Pragma("unroll")                                                    \
        for (int h2 = 0; h2 < 2; ++h2)                                       \
          _Pragma("unroll")                                                  \
          for (int j = 0; j < 8; ++j)                                        \
            pa[qi][h2][j] = (bf16)s[qi][h2 * 2 + (j >> 2)][j & 3];           \
      __builtin_amdgcn_s_setprio(1);                                         \
      _Pragma("unroll")                                                      \
      for (int qi = 0; qi < 2; ++qi) {                                       \
        osum[qi] = __builtin_amdgcn_mfma_f32_16x16x32_bf16(pa[qi][0], vones, osum[qi], 0, 0, 0); \
        osum[qi] = __builtin_amdgcn_mfma_f32_16x16x32_bf16(pa[qi][1], vones, osum[qi], 0, 0, 0); \
      }                                                                      \
      _Pragma("unroll")                                                      \
      for (int db = 0; db < 4; ++db) {                                       \
        _Pragma("unroll")                                                    \
        for (int h2 = 0; h2 < 2; ++h2) {                                     \
          bf16x8 vf = *(const bf16x8*)(vp[db][h2] + (BUF) * 4096);           \
          _Pragma("unroll")                                                  \
          for (int qi = 0; qi < 2; ++qi)                                     \
            o[qi][db] = __builtin_amdgcn_mfma_f32_16x16x32_bf16(pa[qi][h2], vf, o[qi][db], 0, 0, 0); \
        }                                                                    \
      }                                                                      \
      __builtin_amdgcn_s_setprio(0);                                         \
    }                                                                        \
    __syncthreads();                                                         \
  } while (0)

  int t = t0c;
  for (; t + 1 < t1; t += 2) { TILE(t, 0); TILE(t + 1, 1); }
  if (t < t1) TILE(t, 0);

  // ---- write partials: unnormalized O (bf16) [256][64], rowsum [256]
  {
    bf16* ob = po + (size_t)pid * 16384;
#pragma unroll
    for (int qi = 0; qi < 2; ++qi)
#pragma unroll
      for (int db = 0; db < 4; ++db)
#pragma unroll
        for (int r = 0; r < 4; ++r)
          ob[(wid * 32 + qi * 16 + hi * 4 + r) * 64 + db * 16 + ln] = (bf16)o[qi][db][r];
    if (ln == 0) {
#pragma unroll
      for (int qi = 0; qi < 2; ++qi)
#pragma unroll
        for (int r = 0; r < 4; ++r)
          pl[pid * 256 + wid * 32 + qi * 16 + hi * 4 + r] = osum[qi][r];
    }
  }
#undef TILE
}

// ---------------------------------------------------------------------------
// Combine: merge 1-8 chunks -> normalized bf16 attention output [bh][t][d]
// grid 512 = (qb4 0..15) x (bh 0..15) x (half 0..1); 128 q-rows per block
// ---------------------------------------------------------------------------
__global__ __launch_bounds__(256) void attn_combine_kernel(
    const bf16* __restrict__ po, const float* __restrict__ pl,
    bf16* __restrict__ aw) {
  const int cb = blockIdx.x;
  const int qb4 = 15 - (cb >> 5);
  const int r5 = cb & 31;
  const int bh = r5 >> 1, half = r5 & 1;
  const int tid = threadIdx.x;
  const int q_ = half * 128 + (tid >> 1), dc = (tid & 1) * 32;

  const int k = (qb4 + 2) >> 1;          // nch
  static const int OFF[9] = {0, 1120, 1056, 960, 832, 672, 480, 256, 0};
  const int p0 = OFF[k] + ((2 * k - 1) - qb4) * 16 * k + bh * k;

  float sum = 0.f;
  for (int c = 0; c < k; ++c) sum += pl[(p0 + c) * 256 + q_];
  const float inv = 1.0f / sum;

  float acc[32] = {};
  for (int c = 0; c < k; ++c) {
    const bf16* ob = po + (size_t)(p0 + c) * 16384 + q_ * 64 + dc;
#pragma unroll
    for (int cc = 0; cc < 4; ++cc) {
      bf16x8 x = *(const bf16x8*)&ob[cc * 8];
#pragma unroll
      for (int j = 0; j < 8; ++j) acc[cc * 8 + j] += (float)x[j];
    }
  }
  bf16* dst = aw + ((size_t)bh * TT + qb4 * 256 + q_) * 64 + dc;
#pragma unroll
  for (int cc = 0; cc < 4; ++cc) {
    bf16x8 outv;
#pragma unroll
    for (int j = 0; j < 8; ++j) outv[j] = (bf16)(acc[cc * 8 + j] * inv);
    *(bf16x8*)&dst[cc * 8] = outv;
  }
}

// ---------------------------------------------------------------------------
// GEMM 3: out = attn @ wot^T
// ---------------------------------------------------------------------------
__global__ __launch_bounds__(256) void gemm_out_kernel(
    const bf16* __restrict__ A, const bf16* __restrict__ Wot,
    float* __restrict__ out) {
  __shared__ __align__(16) bf16 As[128 * 64];
  __shared__ __align__(16) bf16 Bs[64 * 64];
  const int tid = threadIdx.x;
  const int wid = tid >> 6, lane = tid & 63, ln = lane & 15, hi = lane >> 4;
  const int wr = wid >> 1, wc = wid & 1;
  const int m0 = blockIdx.x * 128, n0 = blockIdx.y * 64;
  const int srow = lane >> 3, srcc = (lane & 7) ^ srow;

  f32x4 acc[4][2] = {};

  for (int k0 = 0; k0 < 512; k0 += 64) {
    const int h = k0 >> 6;
    __syncthreads();
#pragma unroll
    for (int i = 0; i < 4; ++i) {
      const int rb = 32 * wid + 8 * i;
      const int m = m0 + rb + srow;
      const int b = m >> 12, t = m & 4095;
      GLDS(&A[((size_t)(b * HH + h) * TT + t) * HD + srcc * 8], &As[rb * 64]);
    }
#pragma unroll
    for (int i = 0; i < 2; ++i) {
      const int rb = 16 * wid + 8 * i;
      GLDS(&Wot[(size_t)(n0 + rb + srow) * 512 + k0 + srcc * 8], &Bs[rb * 64]);
    }
    __syncthreads();

    bf16x8 af[4][2], bfr[2][2];
#pragma unroll
    for (int mi = 0; mi < 4; ++mi) {
      const int row = wr * 64 + mi * 16 + ln, rs = row & 7;
      af[mi][0] = *(const bf16x8*)&As[row * 64 + ((hi ^ rs) * 8)];
      af[mi][1] = *(const bf16x8*)&As[row * 64 + (((4 + hi) ^ rs) * 8)];
    }
#pragma unroll
    for (int ni = 0; ni < 2; ++ni) {
      const int row = wc * 32 + ni * 16 + ln, rs = row & 7;
      bfr[ni][0] = *(const bf16x8*)&Bs[row * 64 + ((hi ^ rs) * 8)];
      bfr[ni][1] = *(const bf16x8*)&Bs[row * 64 + (((4 + hi) ^ rs) * 8)];
    }
#pragma unroll
    for (int mi = 0; mi < 4; ++mi)
#pragma unroll
      for (int ni = 0; ni < 2; ++ni) {
        acc[mi][ni] = __builtin_amdgcn_mfma_f32_16x16x32_bf16(af[mi][0], bfr[ni][0], acc[mi][ni], 0, 0, 0);
        acc[mi][ni] = __builtin_amdgcn_mfma_f32_16x16x32_bf16(af[mi][1], bfr[ni][1], acc[mi][ni], 0, 0, 0);
      }
  }

#pragma unroll
  for (int mi = 0; mi < 4; ++mi) {
    int rowb = m0 + wr * 64 + mi * 16 + hi * 4;
#pragma unroll
    for (int ni = 0; ni < 2; ++ni) {
      int n = n0 + wc * 32 + ni * 16 + ln;
#pragma unroll
      for (int r = 0; r < 4; ++r)
        out[(size_t)(rowb + r) * 512 + n] = acc[mi][ni][r];
    }
  }
}

extern "C" void kernel_launch(void* const* d_in, const int* in_sizes, int n_in,
                              void* d_out, int out_size, void* d_ws, size_t ws_size,
                              hipStream_t stream) {
  const float* x = (const float*)d_in[0];
  const float* w_qkv = (const float*)d_in[1];
  const float* w_out = (const float*)d_in[2];
  float* out = (float*)d_out;

  const size_t QKV_ELEMS = (size_t)BHD * TT * HD;   // 4,194,304
  bf16* qw = (bf16*)d_ws;
  bf16* kw = qw + QKV_ELEMS;
  bf16* vw = kw + QKV_ELEMS;       // transposed+permuted layout [bh][d][t']
  bf16* aw = vw + QKV_ELEMS;
  bf16* po = aw + QKV_ELEMS;                         // 1152 x 16384 bf16 = 37.7MB
  float* pl = (float*)(po + (size_t)1152 * 16384);   // 1152 x 256 f32
  bf16* wqt = (bf16*)(pl + (size_t)1152 * 256);      // 1536 x 512 bf16
  bf16* wot = wqt + (size_t)1536 * 512;              // 512 x 512 bf16
  bf16* xb = po;   // alias: xb only live before attn_piece writes po

  convert_x_kernel<<<1024, 256, 0, stream>>>(x, xb);
  transpose_w_kernel<<<256, 256, 0, stream>>>(w_qkv, w_out, wqt, wot);
  gemm_qkv_kernel<<<dim3(M_TOT / 128, 1536 / 128), 256, 0, stream>>>(xb, wqt, qw, kw, vw);
  attn_piece_kernel<<<1152, 512, 0, stream>>>(qw, kw, vw, po, pl);
  attn_combine_kernel<<<512, 256, 0, stream>>>(po, pl, aw);
  gemm_out_kernel<<<dim3(M_TOT / 128, 512 / 64), 256, 0, stream>>>(aw, wot, out);
}